// Round 1
// 480.615 us; speedup vs baseline: 1.0112x; 1.0112x over previous
//
#include <hip/hip_runtime.h>
#include <hip/hip_bf16.h>

typedef __attribute__((ext_vector_type(8))) short bf16x8;
typedef __attribute__((ext_vector_type(4))) float floatx4;

#define B_ 32
#define S_ 512
#define H_ 512
#define M_ (B_*S_)       // 16384 rows
#define K_ 512
#define N_ 1024          // 2H

// async global->LDS, 16B per lane, LDS dest = wave-uniform base + lane*16
__device__ __forceinline__ void gload_lds16(const void* g, void* l) {
  __builtin_amdgcn_global_load_lds(
      (const __attribute__((address_space(1))) void*)g,
      (__attribute__((address_space(3))) void*)l, 16, 0, 0);
}

// ---------------- fp32 -> bf16 weight convert ----------------
__global__ void cvt_kernel(const float* __restrict__ src,
                           __hip_bfloat16* __restrict__ dst, int n4) {
  int t = blockIdx.x * 256 + threadIdx.x;
  if (t >= n4) return;
  float4 v = *(const float4*)(src + (size_t)t * 4);
  union { ushort4 u; __hip_bfloat16 h[4]; } pk;
  pk.h[0] = __float2bfloat16(v.x);
  pk.h[1] = __float2bfloat16(v.y);
  pk.h[2] = __float2bfloat16(v.z);
  pk.h[3] = __float2bfloat16(v.w);
  *(ushort4*)((unsigned short*)dst + (size_t)t * 4) = pk.u;
}

// ---------------- window conv (both dirs), writes bf16 x only ----------------
__global__ void conv_kernel(const float* __restrict__ inf, const float* __restrict__ inb,
                            int instride,
                            const float* __restrict__ fpad, const float* __restrict__ bpad,
                            const float* __restrict__ fw, const float* __restrict__ bw,
                            __hip_bfloat16* __restrict__ xaf, __hip_bfloat16* __restrict__ xab) {
  int t = blockIdx.x * 256 + threadIdx.x;      // 0 .. M_*128-1
  int dir = blockIdx.y;
  int row = t >> 7;                            // 0..16383  (= b*S + s)
  int hv  = (t & 127) << 2;                    // h, float4-vectorized
  int s = row & (S_ - 1);
  float4 a = make_float4(0.f, 0.f, 0.f, 0.f);
  if (dir == 0) {
#pragma unroll
    for (int k = 0; k < 5; ++k) {
      float w = fw[k];
      const float* src = (s + k < 4) ? (fpad + (size_t)(s + k) * H_ + hv)
                                     : (inf + (size_t)(row + k - 4) * instride + hv);
      float4 v = *(const float4*)src;
      a.x += w * v.x; a.y += w * v.y; a.z += w * v.z; a.w += w * v.w;
    }
  } else {
#pragma unroll
    for (int k = 0; k < 5; ++k) {
      float w = bw[k];
      const float* src = (s + k < S_) ? (inb + (size_t)(row + k) * instride + hv)
                                      : (bpad + (size_t)(s + k - S_) * H_ + hv);
      float4 v = *(const float4*)src;
      a.x += w * v.x; a.y += w * v.y; a.z += w * v.z; a.w += w * v.w;
    }
  }
  __hip_bfloat16* xa = dir ? xab : xaf;
  union { ushort4 u; __hip_bfloat16 h[4]; } pk;
  pk.h[0] = __float2bfloat16(a.x);
  pk.h[1] = __float2bfloat16(a.y);
  pk.h[2] = __float2bfloat16(a.z);
  pk.h[3] = __float2bfloat16(a.w);
  *(ushort4*)((unsigned short*)xa + (size_t)row * H_ + hv) = pk.u;
}

// ---------------- fused highway GEMM ----------------
// Block: 128 rows x 64 h-cols -> proj cols [h0,h0+64) (nonlin) + [512+h0,..) (gate),
// then x_new = g*x + (1-g)*relu(nl).  A:[M,512] bf16 rm (doubles as residual x).
// W:[1024,512] bf16 rm.  LDS is XOR-swizzled: LDS(row, cc) holds global k-chunk
// cc ^ (row&7) (16B chunks), achieved by permuting the k-offset each staging lane
// FETCHES (global_load_lds's LDS dest is fixed at base+lane*16).
// XCD-aware remap: the 8 h-sibling blocks of one A-panel land on one XCD.
// Epilogue stages the 128x64 output tile through LDS (lA/lB are dead by then)
// and writes it out row-contiguous: full 128B lines (bf16) / 2x128B (fp32).
// Without this, per-lane 2B/4B scattered stores cost 3.8x/1.9x HBM write
// amplification + write-allocate fetches (measured: WRITE_SIZE 127MB vs 33.5MB ideal).
__global__ void hw_gemm(const __hip_bfloat16* __restrict__ Af, const __hip_bfloat16* __restrict__ Ab,
                        const __hip_bfloat16* __restrict__ Wf, const __hip_bfloat16* __restrict__ Wb,
                        const float* __restrict__ biasf, const float* __restrict__ biasb,
                        __hip_bfloat16* __restrict__ Anf, __hip_bfloat16* __restrict__ Anb,
                        float* __restrict__ outp, int final_mode) {
  __shared__ __align__(16) char smem[32768];
  __hip_bfloat16* lA = (__hip_bfloat16*)smem;                    // 128*64 bf16 = 16KB
  __hip_bfloat16* lB = (__hip_bfloat16*)(smem + 16384);          // 128*64 bf16 = 16KB

  const int tid = threadIdx.x;
  const int lane = tid & 63, wave = tid >> 6;
  const int wm = wave >> 1, wn = wave & 1;
  const int quad = lane >> 4, l16 = lane & 15;
  const int dir = blockIdx.z;

  // XCD-aware remap (x-fastest dispatch; round-robin block->XCD assumed; perf-only)
  const int n = blockIdx.y * 8 + blockIdx.x;   // [0,1024) within dir
  const int xcd = n & 7;
  const int h0 = ((n >> 3) & 7) * 64;
  const int m0 = (xcd + (n >> 6) * 8) * 128;

  const __hip_bfloat16* A = dir ? Ab : Af;
  const __hip_bfloat16* Wm = dir ? Wb : Wf;
  const float* bias = dir ? biasb : biasf;
  __hip_bfloat16* An = dir ? Anb : Anf;

  floatx4 acc[4][4];   // [m-subtile][j: 0,1=nonlin  2,3=gate]
#pragma unroll
  for (int i = 0; i < 4; ++i)
#pragma unroll
    for (int j = 0; j < 4; ++j) acc[i][j] = (floatx4){0.f, 0.f, 0.f, 0.f};

  float xs[4][2][4];   // residual snapshot [i][j][r]

  const int srow = lane >> 3;                    // row within 8-row chunk
  const int skk  = (((lane & 7) ^ srow) << 3);   // SWIZZLED k element offset
  const int xkp  = h0 >> 6;                      // kp at which lA holds x cols [h0,h0+64)
  const int sw   = l16 & 7;                      // read-side swizzle key (= row&7)

  // hoisted staging base pointers
  const __hip_bfloat16* aptr[4];
  const __hip_bfloat16* bptr[4];
#pragma unroll
  for (int c = 0; c < 4; ++c) {
    const int chunk = wave * 4 + c;
    const int arow = chunk * 8 + srow;
    aptr[c] = A + (size_t)(m0 + arow) * K_ + skk;
    const int brow = chunk * 8 + srow;
    const int wrow = (brow < 64) ? (h0 + brow) : (512 + h0 + brow - 64);
    bptr[c] = Wm + (size_t)wrow * K_ + skk;
  }

  for (int kp = 0; kp < 8; ++kp) {     // K = 8 * BK(=64)
    const int kb = kp * 64;
#pragma unroll
    for (int c = 0; c < 4; ++c) {
      const int chunk = wave * 4 + c;
      gload_lds16(aptr[c] + kb, &lA[chunk * 512]);
      gload_lds16(bptr[c] + kb, &lB[chunk * 512]);
    }
    __syncthreads();   // drains vmcnt: global_load_lds complete

    if (kp == xkp) {
      // snapshot residual x for the epilogue from the staged (swizzled) A-tile
#pragma unroll
      for (int i = 0; i < 4; ++i)
#pragma unroll
        for (int j = 0; j < 2; ++j)
#pragma unroll
          for (int r = 0; r < 4; ++r) {
            const int ra = wm * 64 + i * 16 + quad * 4 + r;
            const int c2 = wn * 32 + j * 16 + l16;
            xs[i][j][r] = __bfloat162float(
                lA[ra * 64 + ((((c2 >> 3) ^ (ra & 7)) << 3) | (c2 & 7))]);
          }
    }

#pragma unroll
    for (int ks = 0; ks < 2; ++ks) {
      bf16x8 av[4], bv[4];
#pragma unroll
      for (int i = 0; i < 4; ++i) {
        const int ra = wm * 64 + i * 16 + l16;
        av[i] = *(const bf16x8*)&lA[ra * 64 + (((ks * 4 + quad) ^ sw) << 3)];
      }
#pragma unroll
      for (int j = 0; j < 2; ++j) {
        const int rb = wn * 32 + j * 16 + l16;
        bv[j] = *(const bf16x8*)&lB[rb * 64 + (((ks * 4 + quad) ^ sw) << 3)];
      }
#pragma unroll
      for (int j = 0; j < 2; ++j) {
        const int rb = 64 + wn * 32 + j * 16 + l16;
        bv[2 + j] = *(const bf16x8*)&lB[rb * 64 + (((ks * 4 + quad) ^ sw) << 3)];
      }
#pragma unroll
      for (int i = 0; i < 4; ++i)
#pragma unroll
        for (int j = 0; j < 4; ++j)
          acc[i][j] = __builtin_amdgcn_mfma_f32_16x16x32_bf16(av[i], bv[j], acc[i][j], 0, 0, 0);
    }
    __syncthreads();
  }
  // NOTE: trailing __syncthreads() above guarantees no wave still reads lA/lB
  // -> smem is reusable as the epilogue output tile.

  // epilogue: C/D layout col=lane&15, row=quad*4+reg
  const int cbase = h0 + wn * 32 + l16;
  const int cloc = wn * 32 + l16;          // column within the 64-wide tile
  float bnl[2], bgt[2];
#pragma unroll
  for (int j = 0; j < 2; ++j) {
    bnl[j] = bias[cbase + j * 16];
    bgt[j] = bias[512 + cbase + j * 16];
  }

  if (final_mode) {
    // stash fp32 tile [128][64] in LDS (exactly 32KB), then row-contiguous store
    float* ft = (float*)smem;
#pragma unroll
    for (int i = 0; i < 4; ++i) {
      const int rb = wm * 64 + i * 16 + quad * 4;
#pragma unroll
      for (int r = 0; r < 4; ++r) {
#pragma unroll
        for (int j = 0; j < 2; ++j) {
          float pn = acc[i][j][r] + bnl[j];
          float pg = acc[i][j + 2][r] + bgt[j];
          float g = 1.f / (1.f + __expf(-pg));
          float xo = xs[i][j][r];
          ft[(rb + r) * 64 + cloc + j * 16] = g * xo + (1.f - g) * fmaxf(pn, 0.f);
        }
      }
    }
    __syncthreads();
    const float* src = (const float*)smem;
#pragma unroll
    for (int p = 0; p < 8; ++p) {
      const int rl = p * 16 + (tid >> 4);
      const int cc = (tid & 15) * 4;
      float4 v = *(const float4*)&src[rl * 64 + cc];
      *(float4*)&outp[(size_t)(m0 + rl) * N_ + dir * H_ + h0 + cc] = v;
    }
  } else {
    // stash bf16 tile [128][64] in LDS (16KB), then full-line (128B/row) store
    __hip_bfloat16* bt = (__hip_bfloat16*)smem;
#pragma unroll
    for (int i = 0; i < 4; ++i) {
      const int rb = wm * 64 + i * 16 + quad * 4;
#pragma unroll
      for (int r = 0; r < 4; ++r) {
#pragma unroll
        for (int j = 0; j < 2; ++j) {
          float pn = acc[i][j][r] + bnl[j];
          float pg = acc[i][j + 2][r] + bgt[j];
          float g = 1.f / (1.f + __expf(-pg));
          float xo = xs[i][j][r];
          bt[(rb + r) * 64 + cloc + j * 16] =
              __float2bfloat16(g * xo + (1.f - g) * fmaxf(pn, 0.f));
        }
      }
    }
    __syncthreads();
    const unsigned short* src = (const unsigned short*)smem;
#pragma unroll
    for (int p = 0; p < 4; ++p) {
      const int rl = p * 32 + (tid >> 3);
      const int cc = (tid & 7) * 8;                 // 8 bf16 = 16B per lane
      int4 v = *(const int4*)(src + rl * 64 + cc);
      *(int4*)((unsigned short*)An + (size_t)(m0 + rl) * H_ + h0 + cc) = v;
    }
  }
}

extern "C" void kernel_launch(void* const* d_in, const int* in_sizes, int n_in,
                              void* d_out, int out_size, void* d_ws, size_t ws_size,
                              hipStream_t stream) {
  const float* inputs   = (const float*)d_in[0];
  // d_in[1] = masks (unused by reference)
  const float* fwd_pads = (const float*)d_in[2];
  const float* bwd_pads = (const float*)d_in[3];
  const float* fwd_ws_p = (const float*)d_in[4];
  const float* bwd_ws_p = (const float*)d_in[5];
  const float* fwd_hw_W = (const float*)d_in[6];
  const float* fwd_hw_b = (const float*)d_in[7];
  const float* bwd_hw_W = (const float*)d_in[8];
  const float* bwd_hw_b = (const float*)d_in[9];
  float* out = (float*)d_out;

  char* ws = (char*)d_ws;
  size_t off = 0;
  __hip_bfloat16* Wbf = (__hip_bfloat16*)(ws + off); off += (size_t)4194304 * 2;  // 8 matrices [1024,512]
  __hip_bfloat16* xa0f = (__hip_bfloat16*)(ws + off); off += (size_t)M_ * H_ * 2;
  __hip_bfloat16* xa0b = (__hip_bfloat16*)(ws + off); off += (size_t)M_ * H_ * 2;
  __hip_bfloat16* xa1f = (__hip_bfloat16*)(ws + off); off += (size_t)M_ * H_ * 2;
  __hip_bfloat16* xa1b = (__hip_bfloat16*)(ws + off); off += (size_t)M_ * H_ * 2;
  // total ~75 MiB

  // weights -> bf16 (fwd at 0, bwd at +2097152 elements)
  cvt_kernel<<<2048, 256, 0, stream>>>(fwd_hw_W, Wbf, 524288);
  cvt_kernel<<<2048, 256, 0, stream>>>(bwd_hw_W, Wbf + (size_t)2097152, 524288);

  for (int l = 0; l < 2; ++l) {
    const float *inf, *inb;
    int instride;
    if (l == 0) { inf = inputs; inb = inputs; instride = H_; }
    else        { inf = out;    inb = out + H_; instride = N_; }  // read layer-0 output
    conv_kernel<<<dim3(8192, 2), 256, 0, stream>>>(
        inf, inb, instride,
        fwd_pads + (size_t)l * 4 * H_, bwd_pads + (size_t)l * 4 * H_,
        fwd_ws_p + l * 5, bwd_ws_p + l * 5,
        xa0f, xa0b);

    // highway iter 0 (writes bf16 x ping)
    hw_gemm<<<dim3(8, 128, 2), 256, 0, stream>>>(
        xa0f, xa0b,
        Wbf + (size_t)(l * 2) * 524288, Wbf + (size_t)2097152 + (size_t)(l * 2) * 524288,
        fwd_hw_b + (l * 2) * 1024, bwd_hw_b + (l * 2) * 1024,
        xa1f, xa1b, nullptr, 0);

    // highway iter 1 (final: writes d_out[l])
    hw_gemm<<<dim3(8, 128, 2), 256, 0, stream>>>(
        xa1f, xa1b,
        Wbf + (size_t)(l * 2 + 1) * 524288, Wbf + (size_t)2097152 + (size_t)(l * 2 + 1) * 524288,
        fwd_hw_b + (l * 2 + 1) * 1024, bwd_hw_b + (l * 2 + 1) * 1024,
        nullptr, nullptr, out + (size_t)l * M_ * N_, 1);
  }
}

// Round 3
// 422.355 us; speedup vs baseline: 1.1506x; 1.1379x over previous
//
#include <hip/hip_runtime.h>
#include <hip/hip_bf16.h>

typedef __attribute__((ext_vector_type(8))) short bf16x8;
typedef __attribute__((ext_vector_type(4))) float floatx4;

#define B_ 32
#define S_ 512
#define H_ 512
#define M_ (B_*S_)       // 16384 rows
#define K_ 512
#define N_ 1024          // 2H

// async global->LDS, 16B per lane, LDS dest = wave-uniform base + lane*16
__device__ __forceinline__ void gload_lds16(const void* g, void* l) {
  __builtin_amdgcn_global_load_lds(
      (const __attribute__((address_space(1))) void*)g,
      (__attribute__((address_space(3))) void*)l, 16, 0, 0);
}

// ---------------- fp32 -> bf16 weight convert ----------------
__global__ void cvt_kernel(const float* __restrict__ src,
                           __hip_bfloat16* __restrict__ dst, int n4) {
  int t = blockIdx.x * 256 + threadIdx.x;
  if (t >= n4) return;
  float4 v = *(const float4*)(src + (size_t)t * 4);
  union { ushort4 u; __hip_bfloat16 h[4]; } pk;
  pk.h[0] = __float2bfloat16(v.x);
  pk.h[1] = __float2bfloat16(v.y);
  pk.h[2] = __float2bfloat16(v.z);
  pk.h[3] = __float2bfloat16(v.w);
  *(ushort4*)((unsigned short*)dst + (size_t)t * 4) = pk.u;
}

// ---------------- window conv (both dirs), writes bf16 x only ----------------
__global__ void conv_kernel(const float* __restrict__ inf, const float* __restrict__ inb,
                            int instride,
                            const float* __restrict__ fpad, const float* __restrict__ bpad,
                            const float* __restrict__ fw, const float* __restrict__ bw,
                            __hip_bfloat16* __restrict__ xaf, __hip_bfloat16* __restrict__ xab) {
  int t = blockIdx.x * 256 + threadIdx.x;      // 0 .. M_*128-1
  int dir = blockIdx.y;
  int row = t >> 7;                            // 0..16383  (= b*S + s)
  int hv  = (t & 127) << 2;                    // h, float4-vectorized
  int s = row & (S_ - 1);
  float4 a = make_float4(0.f, 0.f, 0.f, 0.f);
  if (dir == 0) {
#pragma unroll
    for (int k = 0; k < 5; ++k) {
      float w = fw[k];
      const float* src = (s + k < 4) ? (fpad + (size_t)(s + k) * H_ + hv)
                                     : (inf + (size_t)(row + k - 4) * instride + hv);
      float4 v = *(const float4*)src;
      a.x += w * v.x; a.y += w * v.y; a.z += w * v.z; a.w += w * v.w;
    }
  } else {
#pragma unroll
    for (int k = 0; k < 5; ++k) {
      float w = bw[k];
      const float* src = (s + k < S_) ? (inb + (size_t)(row + k) * instride + hv)
                                      : (bpad + (size_t)(s + k - S_) * H_ + hv);
      float4 v = *(const float4*)src;
      a.x += w * v.x; a.y += w * v.y; a.z += w * v.z; a.w += w * v.w;
    }
  }
  __hip_bfloat16* xa = dir ? xab : xaf;
  union { ushort4 u; __hip_bfloat16 h[4]; } pk;
  pk.h[0] = __float2bfloat16(a.x);
  pk.h[1] = __float2bfloat16(a.y);
  pk.h[2] = __float2bfloat16(a.z);
  pk.h[3] = __float2bfloat16(a.w);
  *(ushort4*)((unsigned short*)xa + (size_t)row * H_ + hv) = pk.u;
}

// ---------------- fused highway GEMM, 2-phase double-buffered ----------------
// 512 threads (8 waves, 4M x 2N). Tile: 256 rows x 256 proj cols
// (= 128 out cols: nonlin [h0,h0+128) paired with gate [512+h0,...)).
// BK=32 -> per-K-tile LDS = A[256x32] + B[256x32] bf16 = 32KB; double-buffered
// = 64KB STATIC shared (no dynamic-LDS opt-in, no hipFuncSetAttribute — the
// round-2 suspect for the container failure).
// 2-phase (T3-minimum): issue next K-tile's global_load_lds BEFORE ds_read+MFMA
// of current; the single end-of-iter __syncthreads (vmcnt-0 drain) publishes it,
// so HBM latency hides under the 32-MFMA/wave compute phase.
// Swizzle: 64B rows alias banks every 2 rows -> key = (row>>1)&3. LDS slot s of
// row r holds global k-chunk s^key(r); achieved by permuting the STAGING SOURCE
// k-offset (global_load_lds dest is linear), skk = ((lane&3)^((lane>>3)&3))*8.
// Read slot = quad^key -> a read-quad's 16 lanes cover 8 bank-quads = 2-way (free).
// B-tile rows remapped: each wave's 8 j-subtiles = 4 nonlin + 4 gate of the SAME
// out cols -> epilogue pairing wave-local.
// Epilogue stages output through the (dead) LDS -> full-line HBM writes
// (without it: 3.8x/1.9x write amplification, measured round 0).
__global__ __launch_bounds__(512, 2)
void hw_gemm(const __hip_bfloat16* __restrict__ Af, const __hip_bfloat16* __restrict__ Ab,
             const __hip_bfloat16* __restrict__ Wf, const __hip_bfloat16* __restrict__ Wb,
             const float* __restrict__ biasf, const float* __restrict__ biasb,
             __hip_bfloat16* __restrict__ Anf, __hip_bfloat16* __restrict__ Anb,
             float* __restrict__ outp, int final_mode) {
  __shared__ __align__(16) char smem[65536];   // buf0 {A 16K | B 16K} | buf1 {A | B}

  const int tid = threadIdx.x;
  const int lane = tid & 63, wave = tid >> 6;    // 8 waves
  const int wm = wave >> 1, wn = wave & 1;       // 4M x 2N
  const int quad = lane >> 4, l16 = lane & 15;
  const int dir = blockIdx.z;

  const int n = blockIdx.x;                      // [0,256)
  const int by = n & 63, bx = n >> 6;            // h-siblings share (n&7) -> same XCD
  const int m0 = by * 256;
  const int h0 = bx * 128;                       // out-col base

  const __hip_bfloat16* A = dir ? Ab : Af;
  const __hip_bfloat16* Wm = dir ? Wb : Wf;
  const float* bias = dir ? biasb : biasf;
  __hip_bfloat16* An = dir ? Anb : Anf;

  floatx4 acc[4][8];   // [m][j: 0..3 nonlin, 4..7 gate]
#pragma unroll
  for (int i = 0; i < 4; ++i)
#pragma unroll
    for (int j = 0; j < 8; ++j) acc[i][j] = (floatx4){0.f, 0.f, 0.f, 0.f};

  const int srow = lane >> 2;                    // row within 16-row staging chunk
  const int skk  = (((lane & 3) ^ ((lane >> 3) & 3)) << 3);  // swizzled src k offset
  const int key  = (l16 >> 1) & 3;               // read-side swizzle key
  const int xkp0 = bx * 4 + wn * 2;              // K-tiles holding this wave's x cols
  const int xkp1 = xkp0 + 1;

  // hoisted staging base pointers (2 A-chunks + 2 B-chunks per wave, 16 rows each)
  const __hip_bfloat16* aptr[2];
  const __hip_bfloat16* bptr[2];
#pragma unroll
  for (int c = 0; c < 2; ++c) {
    const int chunk = wave * 2 + c;              // [0,16): rows chunk*16..+16
    aptr[c] = A + (size_t)(m0 + chunk * 16 + srow) * K_ + skk;
    const int brow = chunk * 16 + srow;          // LDS B row
    const int wnp = brow >> 7, rr = brow & 127;  // wave-half, row within
    const int wrow = (rr < 64) ? (h0 + wnp * 64 + rr)                // nonlin W row
                               : (512 + h0 + wnp * 64 + (rr - 64));  // gate W row
    bptr[c] = Wm + (size_t)wrow * K_ + skk;
  }

  // prologue: stage K-tile 0 into buffer 0
#pragma unroll
  for (int c = 0; c < 2; ++c) {
    const int chunk = wave * 2 + c;
    gload_lds16(aptr[c], smem + chunk * 1024);
    gload_lds16(bptr[c], smem + 16384 + chunk * 1024);
  }
  __syncthreads();

  unsigned int xsp[4][4][2];   // residual x, bf16-packed row pairs — ALL indices static
  int cur = 0;
  for (int kp = 0; kp < 16; ++kp) {
    const __hip_bfloat16* cA = (const __hip_bfloat16*)(smem + (cur << 15));
    const __hip_bfloat16* cB = (const __hip_bfloat16*)(smem + (cur << 15) + 16384);
    // issue next K-tile's loads into the other buffer (lands at end-of-iter barrier)
    if (kp < 15) {
      char* nb = smem + ((cur ^ 1) << 15);
      const int kb = (kp + 1) * 32;
#pragma unroll
      for (int c = 0; c < 2; ++c) {
        const int chunk = wave * 2 + c;
        gload_lds16(aptr[c] + kb, nb + chunk * 1024);
        gload_lds16(bptr[c] + kb, nb + 16384 + chunk * 1024);
      }
    }
    if (kp == xkp0) {            // snapshot x cols [0,32) of this wave (j=0,1)
      const unsigned short* pA = (const unsigned short*)cA;
#pragma unroll
      for (int i = 0; i < 4; ++i)
#pragma unroll
        for (int jj = 0; jj < 2; ++jj)
#pragma unroll
          for (int rh = 0; rh < 2; ++rh) {
            const int ra0 = wm * 64 + i * 16 + quad * 4 + rh * 2;
            const int ra1 = ra0 + 1;
            const int c2 = jj * 16 + l16;
            unsigned int lo = pA[ra0 * 32 + ((((c2 >> 3) ^ ((ra0 >> 1) & 3)) << 3) | (c2 & 7))];
            unsigned int hi = pA[ra1 * 32 + ((((c2 >> 3) ^ ((ra1 >> 1) & 3)) << 3) | (c2 & 7))];
            xsp[i][jj][rh] = lo | (hi << 16);
          }
    }
    if (kp == xkp1) {            // snapshot x cols [32,64) (j=2,3)
      const unsigned short* pA = (const unsigned short*)cA;
#pragma unroll
      for (int i = 0; i < 4; ++i)
#pragma unroll
        for (int jj = 0; jj < 2; ++jj)
#pragma unroll
          for (int rh = 0; rh < 2; ++rh) {
            const int ra0 = wm * 64 + i * 16 + quad * 4 + rh * 2;
            const int ra1 = ra0 + 1;
            const int c2 = jj * 16 + l16;
            unsigned int lo = pA[ra0 * 32 + ((((c2 >> 3) ^ ((ra0 >> 1) & 3)) << 3) | (c2 & 7))];
            unsigned int hi = pA[ra1 * 32 + ((((c2 >> 3) ^ ((ra1 >> 1) & 3)) << 3) | (c2 & 7))];
            xsp[i][2 + jj][rh] = lo | (hi << 16);
          }
    }
    // compute: 32 MFMA/wave (K=32), bv in two halves of 4 to cap VGPR pressure
    bf16x8 av[4];
#pragma unroll
    for (int i = 0; i < 4; ++i) {
      const int ra = wm * 64 + i * 16 + l16;
      av[i] = *(const bf16x8*)&cA[ra * 32 + ((quad ^ key) << 3)];
    }
#pragma unroll
    for (int jh = 0; jh < 2; ++jh) {
      bf16x8 bv[4];
#pragma unroll
      for (int jj = 0; jj < 4; ++jj) {
        const int rb = wn * 128 + (jh * 4 + jj) * 16 + l16;
        bv[jj] = *(const bf16x8*)&cB[rb * 32 + ((quad ^ key) << 3)];
      }
#pragma unroll
      for (int i = 0; i < 4; ++i)
#pragma unroll
        for (int jj = 0; jj < 4; ++jj)
          acc[i][jh * 4 + jj] =
              __builtin_amdgcn_mfma_f32_16x16x32_bf16(av[i], bv[jj], acc[i][jh * 4 + jj], 0, 0, 0);
    }
    __syncthreads();   // drains vmcnt (next tile staged) + all reads of cur done
    cur ^= 1;
  }
  // smem (all 64KB) is dead now -> reuse as epilogue output tile

  float bnl[4], bgt[4];
#pragma unroll
  for (int j = 0; j < 4; ++j) {
    const int c = h0 + wn * 64 + j * 16 + l16;
    bnl[j] = bias[c];
    bgt[j] = bias[512 + c];
  }

  if (final_mode) {
    // fp32 [256][64] per wn-half = 64KB; two passes, full-line (2x128B/row) stores
    float* ft = (float*)smem;
#pragma unroll
    for (int p = 0; p < 2; ++p) {
      if (wn == p) {
#pragma unroll
        for (int i = 0; i < 4; ++i)
#pragma unroll
          for (int r = 0; r < 4; ++r) {
            const int rl = wm * 64 + i * 16 + quad * 4 + r;
#pragma unroll
            for (int j = 0; j < 4; ++j) {
              float pn = acc[i][j][r] + bnl[j];
              float pg = acc[i][j + 4][r] + bgt[j];
              float g = 1.f / (1.f + __expf(-pg));
              unsigned int u = xsp[i][j][r >> 1];
              unsigned int bits = (r & 1) ? (u >> 16) : (u & 0xffffu);
              float xo = __uint_as_float(bits << 16);
              ft[rl * 64 + j * 16 + l16] = g * xo + (1.f - g) * fmaxf(pn, 0.f);
            }
          }
      }
      __syncthreads();
#pragma unroll
      for (int q = 0; q < 8; ++q) {
        const int rl = q * 32 + (tid >> 4);
        const int cc = (tid & 15) * 4;
        float4 v = *(const float4*)&ft[rl * 64 + cc];
        *(float4*)&outp[(size_t)(m0 + rl) * N_ + dir * H_ + h0 + p * 64 + cc] = v;
      }
      __syncthreads();
    }
  } else {
    // bf16 [256][128] = 64KB; one pass, full-line (2x128B/row) stores
    __hip_bfloat16* bt = (__hip_bfloat16*)smem;
#pragma unroll
    for (int i = 0; i < 4; ++i)
#pragma unroll
      for (int r = 0; r < 4; ++r) {
        const int rl = wm * 64 + i * 16 + quad * 4 + r;
#pragma unroll
        for (int j = 0; j < 4; ++j) {
          float pn = acc[i][j][r] + bnl[j];
          float pg = acc[i][j + 4][r] + bgt[j];
          float g = 1.f / (1.f + __expf(-pg));
          unsigned int u = xsp[i][j][r >> 1];
          unsigned int bits = (r & 1) ? (u >> 16) : (u & 0xffffu);
          float xo = __uint_as_float(bits << 16);
          bt[rl * 128 + wn * 64 + j * 16 + l16] =
              __float2bfloat16(g * xo + (1.f - g) * fmaxf(pn, 0.f));
        }
      }
    __syncthreads();
    const unsigned short* src = (const unsigned short*)smem;
#pragma unroll
    for (int p = 0; p < 8; ++p) {
      const int rl = p * 32 + (tid >> 4);
      const int cc = (tid & 15) * 8;             // 8 bf16 = 16B per lane
      int4 v = *(const int4*)(src + rl * 128 + cc);
      *(int4*)((unsigned short*)An + (size_t)(m0 + rl) * H_ + h0 + cc) = v;
    }
  }
}

extern "C" void kernel_launch(void* const* d_in, const int* in_sizes, int n_in,
                              void* d_out, int out_size, void* d_ws, size_t ws_size,
                              hipStream_t stream) {
  const float* inputs   = (const float*)d_in[0];
  // d_in[1] = masks (unused by reference)
  const float* fwd_pads = (const float*)d_in[2];
  const float* bwd_pads = (const float*)d_in[3];
  const float* fwd_ws_p = (const float*)d_in[4];
  const float* bwd_ws_p = (const float*)d_in[5];
  const float* fwd_hw_W = (const float*)d_in[6];
  const float* fwd_hw_b = (const float*)d_in[7];
  const float* bwd_hw_W = (const float*)d_in[8];
  const float* bwd_hw_b = (const float*)d_in[9];
  float* out = (float*)d_out;

  char* ws = (char*)d_ws;
  size_t off = 0;
  __hip_bfloat16* Wbf = (__hip_bfloat16*)(ws + off); off += (size_t)4194304 * 2;  // 8 matrices [1024,512]
  __hip_bfloat16* xa0f = (__hip_bfloat16*)(ws + off); off += (size_t)M_ * H_ * 2;
  __hip_bfloat16* xa0b = (__hip_bfloat16*)(ws + off); off += (size_t)M_ * H_ * 2;
  __hip_bfloat16* xa1f = (__hip_bfloat16*)(ws + off); off += (size_t)M_ * H_ * 2;
  __hip_bfloat16* xa1b = (__hip_bfloat16*)(ws + off); off += (size_t)M_ * H_ * 2;
  // total ~75 MiB

  // weights -> bf16 (fwd at 0, bwd at +2097152 elements)
  cvt_kernel<<<2048, 256, 0, stream>>>(fwd_hw_W, Wbf, 524288);
  cvt_kernel<<<2048, 256, 0, stream>>>(bwd_hw_W, Wbf + (size_t)2097152, 524288);

  for (int l = 0; l < 2; ++l) {
    const float *inf, *inb;
    int instride;
    if (l == 0) { inf = inputs; inb = inputs; instride = H_; }
    else        { inf = out;    inb = out + H_; instride = N_; }  // read layer-0 output
    conv_kernel<<<dim3(8192, 2), 256, 0, stream>>>(
        inf, inb, instride,
        fwd_pads + (size_t)l * 4 * H_, bwd_pads + (size_t)l * 4 * H_,
        fwd_ws_p + l * 5, bwd_ws_p + l * 5,
        xa0f, xa0b);

    // highway iter 0 (writes bf16 x ping)
    hw_gemm<<<dim3(256, 1, 2), 512, 0, stream>>>(
        xa0f, xa0b,
        Wbf + (size_t)(l * 2) * 524288, Wbf + (size_t)2097152 + (size_t)(l * 2) * 524288,
        fwd_hw_b + (l * 2) * 1024, bwd_hw_b + (l * 2) * 1024,
        xa1f, xa1b, nullptr, 0);

    // highway iter 1 (final: writes d_out[l])
    hw_gemm<<<dim3(256, 1, 2), 512, 0, stream>>>(
        xa1f, xa1b,
        Wbf + (size_t)(l * 2 + 1) * 524288, Wbf + (size_t)2097152 + (size_t)(l * 2 + 1) * 524288,
        fwd_hw_b + (l * 2 + 1) * 1024, bwd_hw_b + (l * 2 + 1) * 1024,
        nullptr, nullptr, out + (size_t)l * M_ * N_, 1);
  }
}